// Round 13
// baseline (616.042 us; speedup 1.0000x reference)
//
#include <hip/hip_runtime.h>
#include <hip/hip_bf16.h>

#define HW 16384
#define NC 256
#define NO 64
#define NPM 1048576          // floats per (b, modality)
#define EPS_IN 1e-5f
#define DBLK 1024            // k_dots blocks.x
#define WIN 1024             // floats per modality per window
#define SPX 128              // pixels per k_gemm block window
#define NPAIR 16             // channel pairs per 32-ch chunk
#define PRW 260              // dwords per pair row: 2*128 + 4 pad

typedef float f32x4 __attribute__((ext_vector_type(4)));
typedef short bhalf8 __attribute__((ext_vector_type(8)));

static __device__ __forceinline__ short f2bf(float f){
  __bf16 h = (__bf16)f;
  return __builtin_bit_cast(short, h);
}

// ws float layout: [256,320) probs[b][m] ; [320,2368) stats[(b*64+o)*2+{s,q}] ;
//                  [8192, +16*DBLK*10) block partials

__global__ void k_zero(float* ws){
  int i = blockIdx.x*256 + threadIdx.x;
  if (i < 2048) ws[320 + i] = 0.f;   // stats only
}

// Pass 1: Gram partials (proven ~50us structure, untouched).
__global__ void k_dots(const float* __restrict__ x, float* __restrict__ partials){
  __shared__ float lds[4][WIN];
  __shared__ float red[4][16];
  const int b = blockIdx.y, bx = blockIdx.x;
  const int tid = threadIdx.x;
  const int w = tid >> 6, lane = tid & 63;
  const int wi = (bx + b*67) & (DBLK-1);
  const float* src = x + (size_t)b*4*NPM + (size_t)w*NPM + (size_t)wi*WIN + lane*4;

  #pragma unroll
  for (int li=0; li<4; li++){
    __builtin_amdgcn_global_load_lds(
        (const __attribute__((address_space(1))) void*)(src + li*256),
        (__attribute__((address_space(3))) void*)&lds[w][li*256],
        16, 0, 0);
  }
  __syncthreads();

  float4 vv[4];
  #pragma unroll
  for (int m=0;m<4;m++) vv[m] = *(const float4*)&lds[m][tid*4];
  float acc[10];
  int k=0;
  #pragma unroll
  for (int i=0;i<4;i++)
    #pragma unroll
    for (int j=i;j<4;j++,k++)
      acc[k] = vv[i].x*vv[j].x + vv[i].y*vv[j].y + vv[i].z*vv[j].z + vv[i].w*vv[j].w;

  #pragma unroll
  for (int kk=0;kk<10;kk++){
    float s = acc[kk];
    #pragma unroll
    for (int off=1; off<64; off<<=1) s += __shfl_xor(s, off, 64);
    acc[kk]=s;
  }
  if (lane==0){
    #pragma unroll
    for (int kk=0;kk<10;kk++) red[w][kk] = acc[kk];
  }
  __syncthreads();
  if (tid<10){
    float s = red[0][tid] + red[1][tid] + red[2][tid] + red[3][tid];
    partials[((size_t)b*DBLK + bx)*10 + tid] = s;
  }
}

__global__ void k_attn(const float* __restrict__ partials, float* __restrict__ probs){
  __shared__ float red[4][16];
  int b = blockIdx.x, tid = threadIdx.x;       // 256 threads
  int w = tid>>6, lane = tid&63;
  float a[10];
  #pragma unroll
  for (int kk=0;kk<10;kk++) a[kk]=0.f;
  #pragma unroll
  for (int r=0;r<DBLK/256;r++){
    const float* p = partials + ((size_t)b*DBLK + r*256 + tid)*10;
    #pragma unroll
    for (int kk=0;kk<10;kk++) a[kk]+=p[kk];
  }
  #pragma unroll
  for (int kk=0;kk<10;kk++){
    float s=a[kk];
    #pragma unroll
    for (int off=1;off<64;off<<=1) s+=__shfl_xor(s,off,64);
    a[kk]=s;
  }
  if (lane==0){
    #pragma unroll
    for (int kk=0;kk<10;kk++) red[w][kk]=a[kk];
  }
  __syncthreads();
  if (tid==0){
    float d[10];
    #pragma unroll
    for (int kk=0;kk<10;kk++) d[kk]=red[0][kk]+red[1][kk]+red[2][kk]+red[3][kk];
    float D[4][4];
    int k2=0;
    #pragma unroll
    for (int i=0;i<4;i++)
      #pragma unroll
      for (int j=i;j<4;j++,k2++){ D[i][j]=d[k2]; D[j][i]=d[k2]; }
    float nrm[4];
    #pragma unroll
    for (int m=0;m<4;m++) nrm[m]=fmaxf(sqrtf(D[m][m]),1e-8f);
    float sc[4];
    #pragma unroll
    for (int i=0;i<4;i++){
      float s=0.f;
      #pragma unroll
      for (int j=0;j<4;j++) s += D[i][j]/(nrm[i]*nrm[j]);
      sc[i] = -(s-1.0f);
    }
    float mx = fmaxf(fmaxf(sc[0],sc[1]), fmaxf(sc[2],sc[3]));
    float e[4], se=0.f;
    #pragma unroll
    for (int m=0;m<4;m++){ e[m]=expf(sc[m]-mx); se+=e[m]; }
    #pragma unroll
    for (int m=0;m<4;m++) probs[b*4+m]=e[m]/se;
  }
}

// GEMM: Y[b] = (W*prob[b]) @ X[b]. R11 counted-vmcnt skeleton, re-geometried:
// 512-thr blocks (8 waves: 4 row-quarters x 2 px-halves), SPX=128, 33KB dbuf
// -> 2 blocks/CU = 16 waves/CU. LDS pair-major [16][2*128+4]: linear
// global_load_lds dest (1KB = one pair), ds_read2-mergeable (c,c+1) reads,
// pad -> conflict-free banks. afrag = 8 frags (32 VGPR).
__launch_bounds__(512, 4)
__global__ void k_gemm(const float* __restrict__ x, const float* __restrict__ w,
                       const float* __restrict__ ws, float* __restrict__ y,
                       float* __restrict__ stats){
  __shared__ float buf[2][NPAIR][PRW];   // 2 x 16.6 KB
  const int b   = blockIdx.y;
  const int pw  = blockIdx.x * SPX;
  const int tid = threadIdx.x;
  const int wid = tid >> 6;
  const int lane = tid & 63;
  const int l15 = lane & 15;
  const int lg  = lane >> 4;
  const int wr  = wid >> 1;     // row quarter: rows wr*16..wr*16+15
  const int wp  = wid & 1;      // pixel half: px wp*64..wp*64+63

  // A fragments: row = wr*16 + l15; k-map e=eh*4+el <-> ch = ks*32 + lg*4 + el + 16*eh
  const float* probs = ws + 256 + b*4;
  float pm[4] = {probs[0], probs[1], probs[2], probs[3]};
  bhalf8 afrag[8];
  const float4* w4 = reinterpret_cast<const float4*>(w);
  {
    int row = wr*16 + l15;
    #pragma unroll
    for (int ks=0; ks<8; ks++){
      float s = pm[ks>>1];
      float4 a0 = w4[row*64 + ks*8 + lg];
      float4 a1 = w4[row*64 + ks*8 + lg + 4];
      bhalf8 f;
      f[0]=f2bf(a0.x*s); f[1]=f2bf(a0.y*s); f[2]=f2bf(a0.z*s); f[3]=f2bf(a0.w*s);
      f[4]=f2bf(a1.x*s); f[5]=f2bf(a1.y*s); f[6]=f2bf(a1.z*s); f[7]=f2bf(a1.w*s);
      afrag[ks] = f;
    }
  }

  const float* xb = x + (size_t)b*NC*HW + pw;

  // stage chunk cc (32 ch) into buf[cur]: 2 instr/wave, each 1KB = one pair
  // (2 channel rows of 128 px). lanes 0-31 -> subrow 0, lanes 32-63 -> subrow 1.
  auto STAGE = [&](int cc, int cur){
    #pragma unroll
    for (int j=0; j<2; j++){
      int pair = wid*2 + j;
      const float* src = xb + (size_t)(cc*32 + pair*2 + (lane>>5))*HW + (lane&31)*4;
      __builtin_amdgcn_global_load_lds(
          (const __attribute__((address_space(1))) void*)src,
          (__attribute__((address_space(3))) void*)&buf[cur][pair][0],
          16, 0, 0);
    }
  };

  f32x4 acc[4];
  #pragma unroll
  for (int pt=0; pt<4; pt++) acc[pt] = (f32x4){0.f,0.f,0.f,0.f};

  STAGE(0, 0);
  int cur = 0;
  #pragma unroll 1
  for (int cc=0; cc<8; cc++){
    if (cc < 7){
      STAGE(cc+1, cur^1);                              // 2 more loads in flight
      asm volatile("s_waitcnt vmcnt(2)" ::: "memory"); // own chunk-cc loads done
    } else {
      asm volatile("s_waitcnt vmcnt(0)" ::: "memory");
    }
    __builtin_amdgcn_s_barrier();        // all waves' chunk-cc writes done
    __builtin_amdgcn_sched_barrier(0);

    const float (*bp)[PRW] = buf[cur];
    #pragma unroll
    for (int pt=0; pt<4; pt++){
      int px = wp*64 + pt*16 + l15;
      bhalf8 bfr;
      #pragma unroll
      for (int eh=0; eh<2; eh++)
        #pragma unroll
        for (int el=0; el<4; el++){
          int c = lg*4 + el + eh*16;                   // 0..31 within chunk
          bfr[eh*4+el] = f2bf(bp[c>>1][(c&1)*128 + px]);
        }
      acc[pt] = __builtin_amdgcn_mfma_f32_16x16x32_bf16(afrag[cc], bfr, acc[pt], 0, 0, 0);
    }

    __builtin_amdgcn_sched_barrier(0);
    __builtin_amdgcn_s_barrier();        // reads done -> buf[cur] reusable
    cur ^= 1;
  }

  // epilogue: y write + stats (C/D: row = lg*4 + r, col = l15)
  float sacc[4] = {0,0,0,0}, qacc[4] = {0,0,0,0};
  #pragma unroll
  for (int pt=0; pt<4; pt++){
    size_t ybase = ((size_t)(b*NO + wr*16 + lg*4))*HW + pw + wp*64 + pt*16 + l15;
    #pragma unroll
    for (int r=0; r<4; r++){
      float v = acc[pt][r];
      y[ybase + (size_t)r*HW] = v;
      sacc[r] += v;
      qacc[r] += v*v;
    }
  }
  #pragma unroll
  for (int r=0; r<4; r++){
    float s = sacc[r], q = qacc[r];
    #pragma unroll
    for (int off=1; off<16; off<<=1){
      s += __shfl_xor(s, off, 64);
      q += __shfl_xor(q, off, 64);
    }
    if (l15 == 0){
      int o = wr*16 + lg*4 + r;
      atomicAdd(&stats[b*128 + o*2],     s);
      atomicAdd(&stats[b*128 + o*2 + 1], q);
    }
  }
}

__global__ void k_norm(float* __restrict__ y, const float* __restrict__ stats){
  int bo = blockIdx.x;
  float s = stats[bo*2], q = stats[bo*2+1];
  float mean = s * (1.f/HW);
  float var  = q * (1.f/HW) - mean*mean;
  float inv  = rsqrtf(var + EPS_IN);
  float4* yp = reinterpret_cast<float4*>(y) + (size_t)bo*(HW/4);
  #pragma unroll 4
  for (int i = threadIdx.x; i < HW/4; i += 256){
    float4 v = yp[i];
    v.x = fmaxf((v.x-mean)*inv, 0.f);
    v.y = fmaxf((v.y-mean)*inv, 0.f);
    v.z = fmaxf((v.z-mean)*inv, 0.f);
    v.w = fmaxf((v.w-mean)*inv, 0.f);
    yp[i] = v;
  }
}

extern "C" void kernel_launch(void* const* d_in, const int* in_sizes, int n_in,
                              void* d_out, int out_size, void* d_ws, size_t ws_size,
                              hipStream_t stream){
  const float* x = (const float*)d_in[0];
  const float* w = (const float*)d_in[1];
  float* out = (float*)d_out;
  float* ws  = (float*)d_ws;
  float* partials = ws + 8192;
  float* probs    = ws + 256;
  float* stats    = ws + 320;

  k_zero<<<dim3(8),          dim3(256), 0, stream>>>(ws);
  k_dots<<<dim3(DBLK,16),    dim3(256), 0, stream>>>(x, partials);
  k_attn<<<dim3(16),         dim3(256), 0, stream>>>(partials, probs);
  k_gemm<<<dim3(HW/SPX,16),  dim3(512), 0, stream>>>(x, w, ws, out, stats);
  k_norm<<<dim3(1024),       dim3(256), 0, stream>>>(out, stats);
}

// Round 14
// 382.439 us; speedup vs baseline: 1.6108x; 1.6108x over previous
//
#include <hip/hip_runtime.h>
#include <hip/hip_bf16.h>

#define HW 16384
#define NC 256
#define NO 64
#define NPM 1048576          // floats per (b, modality)
#define EPS_IN 1e-5f
#define DBLK 1024            // k_dots blocks.x
#define WIN 1024             // floats per modality per window
#define GPX 32               // pixels per k_gemm block

typedef float f32x4 __attribute__((ext_vector_type(4)));
typedef short bhalf8 __attribute__((ext_vector_type(8)));

static __device__ __forceinline__ short f2bf(float f){
  __bf16 h = (__bf16)f;
  return __builtin_bit_cast(short, h);
}

// ws float layout: [256,320) probs[b][m] ; [320,2368) stats[(b*64+o)*2+{s,q}] ;
//                  [8192, +16*DBLK*10) block partials

__global__ void k_zero(float* ws){
  int i = blockIdx.x*256 + threadIdx.x;
  if (i < 2048) ws[320 + i] = 0.f;   // stats only
}

// Pass 1: Gram partials (proven ~50us / 5.4TB/s structure, untouched).
__global__ void k_dots(const float* __restrict__ x, float* __restrict__ partials){
  __shared__ float lds[4][WIN];
  __shared__ float red[4][16];
  const int b = blockIdx.y, bx = blockIdx.x;
  const int tid = threadIdx.x;
  const int w = tid >> 6, lane = tid & 63;
  const int wi = (bx + b*67) & (DBLK-1);
  const float* src = x + (size_t)b*4*NPM + (size_t)w*NPM + (size_t)wi*WIN + lane*4;

  #pragma unroll
  for (int li=0; li<4; li++){
    __builtin_amdgcn_global_load_lds(
        (const __attribute__((address_space(1))) void*)(src + li*256),
        (__attribute__((address_space(3))) void*)&lds[w][li*256],
        16, 0, 0);
  }
  __syncthreads();

  float4 vv[4];
  #pragma unroll
  for (int m=0;m<4;m++) vv[m] = *(const float4*)&lds[m][tid*4];
  float acc[10];
  int k=0;
  #pragma unroll
  for (int i=0;i<4;i++)
    #pragma unroll
    for (int j=i;j<4;j++,k++)
      acc[k] = vv[i].x*vv[j].x + vv[i].y*vv[j].y + vv[i].z*vv[j].z + vv[i].w*vv[j].w;

  #pragma unroll
  for (int kk=0;kk<10;kk++){
    float s = acc[kk];
    #pragma unroll
    for (int off=1; off<64; off<<=1) s += __shfl_xor(s, off, 64);
    acc[kk]=s;
  }
  if (lane==0){
    #pragma unroll
    for (int kk=0;kk<10;kk++) red[w][kk] = acc[kk];
  }
  __syncthreads();
  if (tid<10){
    float s = red[0][tid] + red[1][tid] + red[2][tid] + red[3][tid];
    partials[((size_t)b*DBLK + bx)*10 + tid] = s;
  }
}

__global__ void k_attn(const float* __restrict__ partials, float* __restrict__ probs){
  __shared__ float red[4][16];
  int b = blockIdx.x, tid = threadIdx.x;       // 256 threads
  int w = tid>>6, lane = tid&63;
  float a[10];
  #pragma unroll
  for (int kk=0;kk<10;kk++) a[kk]=0.f;
  #pragma unroll
  for (int r=0;r<DBLK/256;r++){
    const float* p = partials + ((size_t)b*DBLK + r*256 + tid)*10;
    #pragma unroll
    for (int kk=0;kk<10;kk++) a[kk]+=p[kk];
  }
  #pragma unroll
  for (int kk=0;kk<10;kk++){
    float s=a[kk];
    #pragma unroll
    for (int off=1;off<64;off<<=1) s+=__shfl_xor(s,off,64);
    a[kk]=s;
  }
  if (lane==0){
    #pragma unroll
    for (int kk=0;kk<10;kk++) red[w][kk]=a[kk];
  }
  __syncthreads();
  if (tid==0){
    float d[10];
    #pragma unroll
    for (int kk=0;kk<10;kk++) d[kk]=red[0][kk]+red[1][kk]+red[2][kk]+red[3][kk];
    float D[4][4];
    int k2=0;
    #pragma unroll
    for (int i=0;i<4;i++)
      #pragma unroll
      for (int j=i;j<4;j++,k2++){ D[i][j]=d[k2]; D[j][i]=d[k2]; }
    float nrm[4];
    #pragma unroll
    for (int m=0;m<4;m++) nrm[m]=fmaxf(sqrtf(D[m][m]),1e-8f);
    float sc[4];
    #pragma unroll
    for (int i=0;i<4;i++){
      float s=0.f;
      #pragma unroll
      for (int j=0;j<4;j++) s += D[i][j]/(nrm[i]*nrm[j]);
      sc[i] = -(s-1.0f);
    }
    float mx = fmaxf(fmaxf(sc[0],sc[1]), fmaxf(sc[2],sc[3]));
    float e[4], se=0.f;
    #pragma unroll
    for (int m=0;m<4;m++){ e[m]=expf(sc[m]-mx); se+=e[m]; }
    #pragma unroll
    for (int m=0;m<4;m++) probs[b*4+m]=e[m]/se;
  }
}

// GEMM: Y[b] = (W*prob[b]) @ X[b], shaped like k_dots: one-shot 32KB tile
// [256ch][32px] per block, 8192 independent blocks, 5 resident/CU (20
// waves/CU). Load overlap comes from BLOCK-level TLP (k_dots precedent),
// not intra-block pipelining (measured neutral R11). Wave w stages channels
// [w*64, w*64+64) as 8 instrs x 8 rows x 128B; computes rows [w*16, w*16+16).
__launch_bounds__(256, 5)
__global__ void k_gemm(const float* __restrict__ x, const float* __restrict__ w,
                       const float* __restrict__ ws, float* __restrict__ y,
                       float* __restrict__ stats){
  __shared__ float tile[NC][GPX];   // 32 KB exactly
  const int b   = blockIdx.y;
  const int px0 = blockIdx.x * GPX;
  const int tid = threadIdx.x;
  const int wv  = tid >> 6;
  const int lane = tid & 63;
  const int l15 = lane & 15;
  const int lg  = lane >> 4;

  // A fragments: row = wv*16 + l15; k-map (ks,lg,el,eh) -> c = ks*32 + lg*4 + el + 16*eh
  const float* probs = ws + 256 + b*4;
  float pm[4] = {probs[0], probs[1], probs[2], probs[3]};
  bhalf8 afrag[8];
  const float4* w4 = reinterpret_cast<const float4*>(w);
  {
    int row = wv*16 + l15;
    #pragma unroll
    for (int ks=0; ks<8; ks++){
      float s = pm[ks>>1];
      float4 a0 = w4[row*64 + ks*8 + lg];
      float4 a1 = w4[row*64 + ks*8 + lg + 4];
      bhalf8 f;
      f[0]=f2bf(a0.x*s); f[1]=f2bf(a0.y*s); f[2]=f2bf(a0.z*s); f[3]=f2bf(a0.w*s);
      f[4]=f2bf(a1.x*s); f[5]=f2bf(a1.y*s); f[6]=f2bf(a1.z*s); f[7]=f2bf(a1.w*s);
      afrag[ks] = f;
    }
  }

  // stage: instr i covers 8 channel rows of 128B; lane -> row lane>>3, byte (lane&7)*16
  {
    const float* xb = x + (size_t)b*NC*HW + px0;
    #pragma unroll
    for (int i=0; i<8; i++){
      int cbase = (wv*8 + i)*8;
      const float* src = xb + (size_t)(cbase + (lane>>3))*HW + (lane&7)*4;
      __builtin_amdgcn_global_load_lds(
          (const __attribute__((address_space(1))) void*)src,
          (__attribute__((address_space(3))) void*)&tile[cbase][0],
          16, 0, 0);
    }
  }
  __syncthreads();

  f32x4 acc[2];
  acc[0] = (f32x4){0.f,0.f,0.f,0.f};
  acc[1] = (f32x4){0.f,0.f,0.f,0.f};

  #pragma unroll
  for (int ks=0; ks<8; ks++){
    #pragma unroll
    for (int pt=0; pt<2; pt++){
      bhalf8 bfr;
      #pragma unroll
      for (int eh=0; eh<2; eh++)
        #pragma unroll
        for (int el=0; el<4; el++){
          int c = ks*32 + lg*4 + el + eh*16;
          bfr[eh*4+el] = f2bf(tile[c][pt*16 + l15]);
        }
      acc[pt] = __builtin_amdgcn_mfma_f32_16x16x32_bf16(afrag[ks], bfr, acc[pt], 0, 0, 0);
    }
  }

  // epilogue: y write + stats (C/D: row = lg*4 + r, col = l15)
  float sacc[4] = {0,0,0,0}, qacc[4] = {0,0,0,0};
  #pragma unroll
  for (int pt=0; pt<2; pt++){
    size_t ybase = ((size_t)(b*NO + wv*16 + lg*4))*HW + px0 + pt*16 + l15;
    #pragma unroll
    for (int r=0; r<4; r++){
      float v = acc[pt][r];
      y[ybase + (size_t)r*HW] = v;
      sacc[r] += v;
      qacc[r] += v*v;
    }
  }
  #pragma unroll
  for (int r=0; r<4; r++){
    float s = sacc[r], q = qacc[r];
    #pragma unroll
    for (int off=1; off<16; off<<=1){
      s += __shfl_xor(s, off, 64);
      q += __shfl_xor(q, off, 64);
    }
    if (l15 == 0){
      int o = wv*16 + lg*4 + r;
      atomicAdd(&stats[b*128 + o*2],     s);
      atomicAdd(&stats[b*128 + o*2 + 1], q);
    }
  }
}

__global__ void k_norm(float* __restrict__ y, const float* __restrict__ stats){
  int bo = blockIdx.x;
  float s = stats[bo*2], q = stats[bo*2+1];
  float mean = s * (1.f/HW);
  float var  = q * (1.f/HW) - mean*mean;
  float inv  = rsqrtf(var + EPS_IN);
  float4* yp = reinterpret_cast<float4*>(y) + (size_t)bo*(HW/4);
  #pragma unroll 4
  for (int i = threadIdx.x; i < HW/4; i += 256){
    float4 v = yp[i];
    v.x = fmaxf((v.x-mean)*inv, 0.f);
    v.y = fmaxf((v.y-mean)*inv, 0.f);
    v.z = fmaxf((v.z-mean)*inv, 0.f);
    v.w = fmaxf((v.w-mean)*inv, 0.f);
    yp[i] = v;
  }
}

extern "C" void kernel_launch(void* const* d_in, const int* in_sizes, int n_in,
                              void* d_out, int out_size, void* d_ws, size_t ws_size,
                              hipStream_t stream){
  const float* x = (const float*)d_in[0];
  const float* w = (const float*)d_in[1];
  float* out = (float*)d_out;
  float* ws  = (float*)d_ws;
  float* partials = ws + 8192;
  float* probs    = ws + 256;
  float* stats    = ws + 320;

  k_zero<<<dim3(8),          dim3(256), 0, stream>>>(ws);
  k_dots<<<dim3(DBLK,16),    dim3(256), 0, stream>>>(x, partials);
  k_attn<<<dim3(16),         dim3(256), 0, stream>>>(partials, probs);
  k_gemm<<<dim3(HW/GPX,16),  dim3(256), 0, stream>>>(x, w, ws, out, stats);
  k_norm<<<dim3(1024),       dim3(256), 0, stream>>>(out, stats);
}

// Round 18
// 229.108 us; speedup vs baseline: 2.6889x; 1.6692x over previous
//
#include <hip/hip_runtime.h>
#include <hip/hip_bf16.h>

#define HW 16384
#define NC 256
#define NO 64
#define NPM 1048576          // floats per (b, modality)
#define EPS_IN 1e-5f
#define DBLK 1024            // k_dots blocks.x
#define WIN 1024             // floats per modality per window

typedef float f32x4 __attribute__((ext_vector_type(4)));
typedef short bhalf8 __attribute__((ext_vector_type(8)));

static __device__ __forceinline__ short f2bf(float f){
  __bf16 h = (__bf16)f;
  return __builtin_bit_cast(short, h);
}

// ws float layout: [256,320) probs[b][m] ; [320,2368) stats[(b*64+o)*2+{s,q}] ;
//                  [8192, +16*DBLK*10) block partials

__global__ void k_zero(float* ws){
  int i = blockIdx.x*256 + threadIdx.x;
  if (i < 2048) ws[320 + i] = 0.f;   // stats only
}

// Pass 1: Gram partials (proven ~50us / 5.4TB/s structure, untouched).
__global__ void k_dots(const float* __restrict__ x, float* __restrict__ partials){
  __shared__ float lds[4][WIN];
  __shared__ float red[4][16];
  const int b = blockIdx.y, bx = blockIdx.x;
  const int tid = threadIdx.x;
  const int w = tid >> 6, lane = tid & 63;
  const int wi = (bx + b*67) & (DBLK-1);
  const float* src = x + (size_t)b*4*NPM + (size_t)w*NPM + (size_t)wi*WIN + lane*4;

  #pragma unroll
  for (int li=0; li<4; li++){
    __builtin_amdgcn_global_load_lds(
        (const __attribute__((address_space(1))) void*)(src + li*256),
        (__attribute__((address_space(3))) void*)&lds[w][li*256],
        16, 0, 0);
  }
  __syncthreads();

  float4 vv[4];
  #pragma unroll
  for (int m=0;m<4;m++) vv[m] = *(const float4*)&lds[m][tid*4];
  float acc[10];
  int k=0;
  #pragma unroll
  for (int i=0;i<4;i++)
    #pragma unroll
    for (int j=i;j<4;j++,k++)
      acc[k] = vv[i].x*vv[j].x + vv[i].y*vv[j].y + vv[i].z*vv[j].z + vv[i].w*vv[j].w;

  #pragma unroll
  for (int kk=0;kk<10;kk++){
    float s = acc[kk];
    #pragma unroll
    for (int off=1; off<64; off<<=1) s += __shfl_xor(s, off, 64);
    acc[kk]=s;
  }
  if (lane==0){
    #pragma unroll
    for (int kk=0;kk<10;kk++) red[w][kk] = acc[kk];
  }
  __syncthreads();
  if (tid<10){
    float s = red[0][tid] + red[1][tid] + red[2][tid] + red[3][tid];
    partials[((size_t)b*DBLK + bx)*10 + tid] = s;
  }
}

__global__ void k_attn(const float* __restrict__ partials, float* __restrict__ probs){
  __shared__ float red[4][16];
  int b = blockIdx.x, tid = threadIdx.x;       // 256 threads
  int w = tid>>6, lane = tid&63;
  float a[10];
  #pragma unroll
  for (int kk=0;kk<10;kk++) a[kk]=0.f;
  #pragma unroll
  for (int r=0;r<DBLK/256;r++){
    const float* p = partials + ((size_t)b*DBLK + r*256 + tid)*10;
    #pragma unroll
    for (int kk=0;kk<10;kk++) a[kk]+=p[kk];
  }
  #pragma unroll
  for (int kk=0;kk<10;kk++){
    float s=a[kk];
    #pragma unroll
    for (int off=1;off<64;off<<=1) s+=__shfl_xor(s,off,64);
    a[kk]=s;
  }
  if (lane==0){
    #pragma unroll
    for (int kk=0;kk<10;kk++) red[w][kk]=a[kk];
  }
  __syncthreads();
  if (tid==0){
    float d[10];
    #pragma unroll
    for (int kk=0;kk<10;kk++) d[kk]=red[0][kk]+red[1][kk]+red[2][kk]+red[3][kk];
    float D[4][4];
    int k2=0;
    #pragma unroll
    for (int i=0;i<4;i++)
      #pragma unroll
      for (int j=i;j<4;j++,k2++){ D[i][j]=d[k2]; D[j][i]=d[k2]; }
    float nrm[4];
    #pragma unroll
    for (int m=0;m<4;m++) nrm[m]=fmaxf(sqrtf(D[m][m]),1e-8f);
    float sc[4];
    #pragma unroll
    for (int i=0;i<4;i++){
      float s=0.f;
      #pragma unroll
      for (int j=0;j<4;j++) s += D[i][j]/(nrm[i]*nrm[j]);
      sc[i] = -(s-1.0f);
    }
    float mx = fmaxf(fmaxf(sc[0],sc[1]), fmaxf(sc[2],sc[3]));
    float e[4], se=0.f;
    #pragma unroll
    for (int m=0;m<4;m++){ e[m]=expf(sc[m]-mx); se+=e[m]; }
    #pragma unroll
    for (int m=0;m<4;m++) probs[b*4+m]=e[m]/se;
  }
}

// GEMM: EXACT revert to the round-2 kernel (best measured ~75us by total
// arithmetic, twice confirmed). Direct global gather, 512 resident blocks,
// 4 waves x (64 rows x 16px/it) x 8 its, afrag[4][8] register-resident,
// NO px skew (the R4 skew caused the 3x regression).
__launch_bounds__(256, 2)
__global__ void k_gemm(const float* __restrict__ x, const float* __restrict__ w,
                       const float* __restrict__ ws, float* __restrict__ y,
                       float* __restrict__ stats){
  const int b   = blockIdx.y;
  const int wid = threadIdx.x >> 6;
  const int lane = threadIdx.x & 63;
  const int l15 = lane & 15;
  const int lg  = lane >> 4;

  const float* probs = ws + 256 + b*4;
  float pm[4] = {probs[0], probs[1], probs[2], probs[3]};

  // A frags: row = rt*16 + l15; k-map (lg,el,eh) -> c = ks*32 + lg*4 + el + 16*eh
  bhalf8 afrag[4][8];
  const float4* w4 = reinterpret_cast<const float4*>(w);
  #pragma unroll
  for (int rt=0; rt<4; rt++){
    int row = rt*16 + l15;
    #pragma unroll
    for (int ks=0; ks<8; ks++){
      float s = pm[ks>>1];
      float4 a0 = w4[row*64 + ks*8 + lg];
      float4 a1 = w4[row*64 + ks*8 + lg + 4];
      bhalf8 f;
      f[0]=f2bf(a0.x*s); f[1]=f2bf(a0.y*s); f[2]=f2bf(a0.z*s); f[3]=f2bf(a0.w*s);
      f[4]=f2bf(a1.x*s); f[5]=f2bf(a1.y*s); f[6]=f2bf(a1.z*s); f[7]=f2bf(a1.w*s);
      afrag[rt][ks] = f;
    }
  }

  const float* xb = x + (size_t)b*NC*HW;
  float sacc[4][4] = {{0}}, qacc[4][4] = {{0}};
  const int base = blockIdx.x * 512;

  #pragma unroll 1
  for (int it=0; it<8; it++){
    int n0 = base + wid*16 + it*64;
    f32x4 acc[4];
    #pragma unroll
    for (int rt=0; rt<4; rt++) acc[rt] = (f32x4){0.f,0.f,0.f,0.f};

    #pragma unroll
    for (int ks=0; ks<8; ks++){
      bhalf8 bfr;
      #pragma unroll
      for (int eh=0; eh<2; eh++)
        #pragma unroll
        for (int el=0; el<4; el++){
          int c = ks*32 + lg*4 + el + eh*16;
          bfr[eh*4+el] = f2bf(xb[(size_t)c*HW + n0 + l15]);
        }
      #pragma unroll
      for (int rt=0; rt<4; rt++)
        acc[rt] = __builtin_amdgcn_mfma_f32_16x16x32_bf16(afrag[rt][ks], bfr, acc[rt], 0, 0, 0);
    }

    // C/D layout (verified): row = (lane>>4)*4 + reg, col = lane&15
    size_t ybase = ((size_t)b*NO)*HW + n0 + l15;
    #pragma unroll
    for (int rt=0; rt<4; rt++){
      #pragma unroll
      for (int r=0; r<4; r++){
        int o = rt*16 + lg*4 + r;
        float v = acc[rt][r];
        y[ybase + (size_t)o*HW] = v;
        sacc[rt][r] += v;
        qacc[rt][r] += v*v;
      }
    }
  }

  // stats: reduce the 16 pixels (lanes with same lg) then atomics
  #pragma unroll
  for (int rt=0; rt<4; rt++){
    #pragma unroll
    for (int r=0; r<4; r++){
      float s = sacc[rt][r], q = qacc[rt][r];
      #pragma unroll
      for (int off=1; off<16; off<<=1){
        s += __shfl_xor(s, off, 64);
        q += __shfl_xor(q, off, 64);
      }
      if (l15 == 0){
        int o = rt*16 + lg*4 + r;
        atomicAdd(&stats[(b*NO + o)*2],     s);
        atomicAdd(&stats[(b*NO + o)*2 + 1], q);
      }
    }
  }
}

__global__ void k_norm(float* __restrict__ y, const float* __restrict__ stats){
  int bo = blockIdx.x;
  float s = stats[bo*2], q = stats[bo*2+1];
  float mean = s * (1.f/HW);
  float var  = q * (1.f/HW) - mean*mean;
  float inv  = rsqrtf(var + EPS_IN);
  float4* yp = reinterpret_cast<float4*>(y) + (size_t)bo*(HW/4);
  #pragma unroll 4
  for (int i = threadIdx.x; i < HW/4; i += 256){
    float4 v = yp[i];
    v.x = fmaxf((v.x-mean)*inv, 0.f);
    v.y = fmaxf((v.y-mean)*inv, 0.f);
    v.z = fmaxf((v.z-mean)*inv, 0.f);
    v.w = fmaxf((v.w-mean)*inv, 0.f);
    yp[i] = v;
  }
}

extern "C" void kernel_launch(void* const* d_in, const int* in_sizes, int n_in,
                              void* d_out, int out_size, void* d_ws, size_t ws_size,
                              hipStream_t stream){
  const float* x = (const float*)d_in[0];
  const float* w = (const float*)d_in[1];
  float* out = (float*)d_out;
  float* ws  = (float*)d_ws;
  float* partials = ws + 8192;
  float* probs    = ws + 256;
  float* stats    = ws + 320;

  k_zero<<<dim3(8),          dim3(256), 0, stream>>>(ws);
  k_dots<<<dim3(DBLK,16),    dim3(256), 0, stream>>>(x, partials);
  k_attn<<<dim3(16),         dim3(256), 0, stream>>>(partials, probs);
  k_gemm<<<dim3(32,16),      dim3(256), 0, stream>>>(x, w, ws, out, stats);
  k_norm<<<dim3(1024),       dim3(256), 0, stream>>>(out, stats);
}

// Round 21
// 224.642 us; speedup vs baseline: 2.7423x; 1.0199x over previous
//
#include <hip/hip_runtime.h>
#include <hip/hip_bf16.h>

#define HW 16384
#define NC 256
#define NO 64
#define NPM 1048576          // floats per (b, modality)
#define EPS_IN 1e-5f
#define DBLK 1024            // k_dots blocks.x
#define WIN 1024             // floats per modality per window
#define SPX 512              // pixels per k_gemm block window
#define CHK 32               // channels per staged chunk
#define PRW 516              // dwords per row: 512 + 4 pad

typedef float f32x4 __attribute__((ext_vector_type(4)));
typedef short bhalf8 __attribute__((ext_vector_type(8)));

static __device__ __forceinline__ short f2bf(float f){
  __bf16 h = (__bf16)f;
  return __builtin_bit_cast(short, h);
}

// ws float layout: [256,320) probs[b][m] ; [320,2368) stats[(b*64+o)*2+{s,q}] ;
//                  [8192, +16*DBLK*10) block partials

__global__ void k_zero(float* ws){
  int i = blockIdx.x*256 + threadIdx.x;
  if (i < 2048) ws[320 + i] = 0.f;   // stats only
}

// Pass 1: Gram partials (proven ~50us / 5.4TB/s structure, untouched).
__global__ void k_dots(const float* __restrict__ x, float* __restrict__ partials){
  __shared__ float lds[4][WIN];
  __shared__ float red[4][16];
  const int b = blockIdx.y, bx = blockIdx.x;
  const int tid = threadIdx.x;
  const int w = tid >> 6, lane = tid & 63;
  const int wi = (bx + b*67) & (DBLK-1);
  const float* src = x + (size_t)b*4*NPM + (size_t)w*NPM + (size_t)wi*WIN + lane*4;

  #pragma unroll
  for (int li=0; li<4; li++){
    __builtin_amdgcn_global_load_lds(
        (const __attribute__((address_space(1))) void*)(src + li*256),
        (__attribute__((address_space(3))) void*)&lds[w][li*256],
        16, 0, 0);
  }
  __syncthreads();

  float4 vv[4];
  #pragma unroll
  for (int m=0;m<4;m++) vv[m] = *(const float4*)&lds[m][tid*4];
  float acc[10];
  int k=0;
  #pragma unroll
  for (int i=0;i<4;i++)
    #pragma unroll
    for (int j=i;j<4;j++,k++)
      acc[k] = vv[i].x*vv[j].x + vv[i].y*vv[j].y + vv[i].z*vv[j].z + vv[i].w*vv[j].w;

  #pragma unroll
  for (int kk=0;kk<10;kk++){
    float s = acc[kk];
    #pragma unroll
    for (int off=1; off<64; off<<=1) s += __shfl_xor(s, off, 64);
    acc[kk]=s;
  }
  if (lane==0){
    #pragma unroll
    for (int kk=0;kk<10;kk++) red[w][kk] = acc[kk];
  }
  __syncthreads();
  if (tid<10){
    float s = red[0][tid] + red[1][tid] + red[2][tid] + red[3][tid];
    partials[((size_t)b*DBLK + bx)*10 + tid] = s;
  }
}

__global__ void k_attn(const float* __restrict__ partials, float* __restrict__ probs){
  __shared__ float red[4][16];
  int b = blockIdx.x, tid = threadIdx.x;       // 256 threads
  int w = tid>>6, lane = tid&63;
  float a[10];
  #pragma unroll
  for (int kk=0;kk<10;kk++) a[kk]=0.f;
  #pragma unroll
  for (int r=0;r<DBLK/256;r++){
    const float* p = partials + ((size_t)b*DBLK + r*256 + tid)*10;
    #pragma unroll
    for (int kk=0;kk<10;kk++) a[kk]+=p[kk];
  }
  #pragma unroll
  for (int kk=0;kk<10;kk++){
    float s=a[kk];
    #pragma unroll
    for (int off=1;off<64;off<<=1) s+=__shfl_xor(s,off,64);
    a[kk]=s;
  }
  if (lane==0){
    #pragma unroll
    for (int kk=0;kk<10;kk++) red[w][kk]=a[kk];
  }
  __syncthreads();
  if (tid==0){
    float d[10];
    #pragma unroll
    for (int kk=0;kk<10;kk++) d[kk]=red[0][kk]+red[1][kk]+red[2][kk]+red[3][kk];
    float D[4][4];
    int k2=0;
    #pragma unroll
    for (int i=0;i<4;i++)
      #pragma unroll
      for (int j=i;j<4;j++,k2++){ D[i][j]=d[k2]; D[j][i]=d[k2]; }
    float nrm[4];
    #pragma unroll
    for (int m=0;m<4;m++) nrm[m]=fmaxf(sqrtf(D[m][m]),1e-8f);
    float sc[4];
    #pragma unroll
    for (int i=0;i<4;i++){
      float s=0.f;
      #pragma unroll
      for (int j=0;j<4;j++) s += D[i][j]/(nrm[i]*nrm[j]);
      sc[i] = -(s-1.0f);
    }
    float mx = fmaxf(fmaxf(sc[0],sc[1]), fmaxf(sc[2],sc[3]));
    float e[4], se=0.f;
    #pragma unroll
    for (int m=0;m<4;m++){ e[m]=expf(sc[m]-mx); se+=e[m]; }
    #pragma unroll
    for (int m=0;m<4;m++) probs[b*4+m]=e[m]/se;
  }
}

// GEMM: R11's proven counted-vmcnt dbuf skeleton, re-geometried for DRAM run
// length: SPX=512 -> each staged channel row is 2KB CONTIGUOUS (vs R11's 1KB).
// 132KB LDS dbuf, 1 block/CU, 8 waves (4 px-quarters x 2 och-halves), 512
// blocks (2 gens). 8 staging instr/wave in flight across barriers (vmcnt(8)).
__launch_bounds__(512, 2)
__global__ void k_gemm(const float* __restrict__ x, const float* __restrict__ w,
                       const float* __restrict__ ws, float* __restrict__ y,
                       float* __restrict__ stats){
  __shared__ float buf[2][CHK][PRW];   // 132,096 B
  const int b   = blockIdx.y;
  const int px0 = blockIdx.x * SPX;
  const int tid = threadIdx.x;
  const int wid = tid >> 6;
  const int lane = tid & 63;
  const int l15 = lane & 15;
  const int lg  = lane >> 4;
  const int q   = wid >> 1;     // px quarter: 128 px
  const int h   = wid & 1;      // och half: 32 rows

  // A fragments: row = h*32 + rt*16 + l15; k-map (lg,el,eh) -> c = ks*32 + lg*4 + el + 16*eh
  const float* probs = ws + 256 + b*4;
  float pm[4] = {probs[0], probs[1], probs[2], probs[3]};
  bhalf8 afrag[2][8];
  const float4* w4 = reinterpret_cast<const float4*>(w);
  #pragma unroll
  for (int rt=0; rt<2; rt++){
    int row = h*32 + rt*16 + l15;
    #pragma unroll
    for (int ks=0; ks<8; ks++){
      float s = pm[ks>>1];
      float4 a0 = w4[row*64 + ks*8 + lg];
      float4 a1 = w4[row*64 + ks*8 + lg + 4];
      bhalf8 f;
      f[0]=f2bf(a0.x*s); f[1]=f2bf(a0.y*s); f[2]=f2bf(a0.z*s); f[3]=f2bf(a0.w*s);
      f[4]=f2bf(a1.x*s); f[5]=f2bf(a1.y*s); f[6]=f2bf(a1.z*s); f[7]=f2bf(a1.w*s);
      afrag[rt][ks] = f;
    }
  }

  const float* xb = x + (size_t)b*NC*HW + px0;

  // stage chunk cc (32 rows x 512 px): wave stages 4 rows, 2 instr/row (1KB each,
  // 2KB contiguous per row). LDS dest linear; pad untouched.
  auto STAGE = [&](int cc, int cur){
    #pragma unroll
    for (int rr=0; rr<4; rr++){
      int row = wid*4 + rr;
      const float* src = xb + (size_t)(cc*CHK + row)*HW + lane*4;
      #pragma unroll
      for (int j=0; j<2; j++){
        __builtin_amdgcn_global_load_lds(
            (const __attribute__((address_space(1))) void*)(src + j*256),
            (__attribute__((address_space(3))) void*)&buf[cur][row][j*256],
            16, 0, 0);
      }
    }
  };

  f32x4 acc[2][8];
  #pragma unroll
  for (int rt=0; rt<2; rt++)
    #pragma unroll
    for (int pt=0; pt<8; pt++) acc[rt][pt] = (f32x4){0.f,0.f,0.f,0.f};

  STAGE(0, 0);
  int cur = 0;
  #pragma unroll 1
  for (int cc=0; cc<8; cc++){
    if (cc < 7){
      STAGE(cc+1, cur^1);                              // 8 loads stay in flight
      asm volatile("s_waitcnt vmcnt(8)" ::: "memory"); // chunk cc complete
    } else {
      asm volatile("s_waitcnt vmcnt(0)" ::: "memory");
    }
    __builtin_amdgcn_s_barrier();        // all waves' writes to buf[cur] done
    __builtin_amdgcn_sched_barrier(0);   // no LDS-read hoisting (rule #18)

    const float (*bp)[PRW] = buf[cur];
    #pragma unroll
    for (int pt=0; pt<8; pt++){
      int px = q*128 + pt*16 + l15;
      bhalf8 bfr;
      #pragma unroll
      for (int eh=0; eh<2; eh++)
        #pragma unroll
        for (int el=0; el<4; el++){
          int c = lg*4 + el + eh*16;
          bfr[eh*4+el] = f2bf(bp[c][px]);
        }
      #pragma unroll
      for (int rt=0; rt<2; rt++)
        acc[rt][pt] = __builtin_amdgcn_mfma_f32_16x16x32_bf16(afrag[rt][cc], bfr, acc[rt][pt], 0, 0, 0);
    }

    __builtin_amdgcn_sched_barrier(0);
    __builtin_amdgcn_s_barrier();        // reads done -> buf[cur] reusable
    cur ^= 1;
  }

  // epilogue: y write + stats (C/D: row = lg*4 + r, col = l15)
  float sacc[2][4] = {{0}}, qacc[2][4] = {{0}};
  #pragma unroll
  for (int rt=0; rt<2; rt++){
    #pragma unroll
    for (int pt=0; pt<8; pt++){
      size_t ybase = ((size_t)(b*NO + h*32 + rt*16 + lg*4))*HW + px0 + q*128 + pt*16 + l15;
      #pragma unroll
      for (int r=0; r<4; r++){
        float v = acc[rt][pt][r];
        y[ybase + (size_t)r*HW] = v;
        sacc[rt][r] += v;
        qacc[rt][r] += v*v;
      }
    }
  }
  #pragma unroll
  for (int rt=0; rt<2; rt++){
    #pragma unroll
    for (int r=0; r<4; r++){
      float s = sacc[rt][r], q2 = qacc[rt][r];
      #pragma unroll
      for (int off=1; off<16; off<<=1){
        s  += __shfl_xor(s,  off, 64);
        q2 += __shfl_xor(q2, off, 64);
      }
      if (l15 == 0){
        int o = h*32 + rt*16 + lg*4 + r;
        atomicAdd(&stats[(b*NO + o)*2],     s);
        atomicAdd(&stats[(b*NO + o)*2 + 1], q2);
      }
    }
  }
}

__global__ void k_norm(float* __restrict__ y, const float* __restrict__ stats){
  int bo = blockIdx.x;
  float s = stats[bo*2], q = stats[bo*2+1];
  float mean = s * (1.f/HW);
  float var  = q * (1.f/HW) - mean*mean;
  float inv  = rsqrtf(var + EPS_IN);
  float4* yp = reinterpret_cast<float4*>(y) + (size_t)bo*(HW/4);
  #pragma unroll 4
  for (int i = threadIdx.x; i < HW/4; i += 256){
    float4 v = yp[i];
    v.x = fmaxf((v.x-mean)*inv, 0.f);
    v.y = fmaxf((v.y-mean)*inv, 0.f);
    v.z = fmaxf((v.z-mean)*inv, 0.f);
    v.w = fmaxf((v.w-mean)*inv, 0.f);
    yp[i] = v;
  }
}

extern "C" void kernel_launch(void* const* d_in, const int* in_sizes, int n_in,
                              void* d_out, int out_size, void* d_ws, size_t ws_size,
                              hipStream_t stream){
  const float* x = (const float*)d_in[0];
  const float* w = (const float*)d_in[1];
  float* out = (float*)d_out;
  float* ws  = (float*)d_ws;
  float* partials = ws + 8192;
  float* probs    = ws + 256;
  float* stats    = ws + 320;

  k_zero<<<dim3(8),          dim3(256), 0, stream>>>(ws);
  k_dots<<<dim3(DBLK,16),    dim3(256), 0, stream>>>(x, partials);
  k_attn<<<dim3(16),         dim3(256), 0, stream>>>(partials, probs);
  k_gemm<<<dim3(HW/SPX,16),  dim3(512), 0, stream>>>(x, w, ws, out, stats);
  k_norm<<<dim3(1024),       dim3(256), 0, stream>>>(out, stats);
}